// Round 15
// baseline (382.553 us; speedup 1.0000x reference)
//
#include <hip/hip_runtime.h>
#include <hip/hip_bf16.h>
#include <math.h>

typedef __bf16 bf16x8 __attribute__((ext_vector_type(8)));
typedef float f32x4 __attribute__((ext_vector_type(4)));
typedef unsigned short u16x8 __attribute__((ext_vector_type(8)));

constexpr int EDIM = 256;
constexpr int NE = 1024;
constexpr int NROWS = 65536;
constexpr float BETA = 0.25f;

// ---------------- ws layout (bytes) ----------------
constexpr size_t A2T_OFF   = 0;                          // [1024 mtile][16 chunk][4 kg][64 row][16B]
constexpr size_t A2T_SZ    = (size_t)1024 * 16 * 4096;   // 64 MB
constexpr size_t B2T_OFF   = A2T_OFF + A2T_SZ;           // [128 chunk][8192B]: per nt 16 (8 hi + 8 lo)
constexpr size_t B2T_SZ    = (size_t)8 * 16 * 8192;      // 1 MB
constexpr size_t SZROW_OFF = B2T_OFF + B2T_SZ;           // 65536 f32 (also absorbs g=128 dummy prefetch)
constexpr size_t SZABS_OFF = SZROW_OFF + 262144;         // 65536 f32
constexpr size_t CNORM_OFF = SZABS_OFF + 262144;         // 1024 f32
constexpr size_t EMAX_OFF  = CNORM_OFF + 4096;           // 1 f32 (atomicMax target)
constexpr size_t CNT_OFF   = EMAX_OFF + 256;             // 1 i32
constexpr size_t LIST_OFF  = CNT_OFF + 256;              // 65536 i32
constexpr size_t LPART_OFF = LIST_OFF + 262144;          // 65536 f32
constexpr size_t LP2_OFF   = LPART_OFF + 262144;         // 256 f32
constexpr size_t WS_NEED   = LP2_OFF + 1024;             // ~66 MB

__device__ __forceinline__ unsigned short f32_to_bf16_rne(float f) {
    unsigned u = __float_as_uint(f);
    u += 0x7fffu + ((u >> 16) & 1u);
    return (unsigned short)(u >> 16);
}
__device__ __forceinline__ float bf16_to_f32(unsigned short h) {
    return __uint_as_float((unsigned)h << 16);
}

#define GLL16(g, l)                                                                   \
    __builtin_amdgcn_global_load_lds(                                                 \
        (const __attribute__((address_space(1))) unsigned int*)(g),                   \
        (__attribute__((address_space(3))) unsigned int*)(l), 16, 0, 0)

// ---------------- P3: codebook: cnorm exact, hi/lo bf16 -> B2t, atomicMax |e| ----------------
__global__ __launch_bounds__(64)
void p3_codebook(const float* __restrict__ cb, float* __restrict__ cnorm,
                 char* __restrict__ B2t, unsigned* __restrict__ emax_u) {
    __shared__ float xr[256];
    __shared__ float rres[16];
    __shared__ unsigned short ehi[256], elo[256];
    const int e = blockIdx.x, l = threadIdx.x;
    const float4 v = reinterpret_cast<const float4*>(cb + (size_t)e * EDIM)[l];
    *reinterpret_cast<float4*>(&xr[l * 4]) = v;
    float amax = fmaxf(fmaxf(fabsf(v.x), fabsf(v.y)), fmaxf(fabsf(v.z), fabsf(v.w)));
    #pragma unroll
    for (int off = 32; off; off >>= 1) amax = fmaxf(amax, __shfl_down(amax, off));
    __syncthreads();
    #pragma unroll
    for (int i = 0; i < 4; ++i) {
        const int idx = i * 64 + l;
        const float f = xr[idx];
        const unsigned short h = f32_to_bf16_rne(f);
        ehi[idx] = h;
        elo[idx] = f32_to_bf16_rne(f - bf16_to_f32(h));
    }
    if (l < 16) {
        const float* x = xr + (l >> 3) * 128;
        const int j = l & 7;
        float r = __fmul_rn(x[j], x[j]);
        for (int i = 8; i < 128; i += 8) r = __fadd_rn(r, __fmul_rn(x[i + j], x[i + j]));
        rres[l] = r;
    }
    __syncthreads();
    if (l == 0) {
        float h0 = __fadd_rn(__fadd_rn(__fadd_rn(rres[0], rres[1]), __fadd_rn(rres[2], rres[3])),
                             __fadd_rn(__fadd_rn(rres[4], rres[5]), __fadd_rn(rres[6], rres[7])));
        float h1 = __fadd_rn(__fadd_rn(__fadd_rn(rres[8], rres[9]), __fadd_rn(rres[10], rres[11])),
                             __fadd_rn(__fadd_rn(rres[12], rres[13]), __fadd_rn(rres[14], rres[15])));
        cnorm[e] = __fadd_rn(h0, h1);
        atomicMax(emax_u, __float_as_uint(amax));   // amax >= 0: bit-order == float-order
    }
    // B2t: global chunk g = (e>>7)*16 + c ; c 0-7 = ehi k-block c, c 8-15 = elo k-block c-8
    {
        const int c = l >> 2, kgv = l & 3;   // 64 slots exactly
        const int colbase = ((c < 8) ? c * 32 : (c - 8) * 32) + kgv * 8;
        const unsigned short* src = (c < 8) ? ehi : elo;
        char* dst = B2t + ((((size_t)(e >> 7) * 16 + c) * 512 + (size_t)kgv * 128 + (e & 127)) * 16);
        *reinterpret_cast<uint4*>(dst) = *reinterpret_cast<const uint4*>(&src[colbase]);
    }
}

// ---------------- P2 (fused stats): z -> A2t hi/lo tiles + per-row ||z||^2/sum|z| ----------------
__global__ __launch_bounds__(256)
void p2_atile(const float* __restrict__ z, char* __restrict__ A2t,
              float* __restrict__ szrow, float* __restrict__ szabs) {
    __shared__ float t[64][260];
    __shared__ float ch[64][16];
    const int mt = blockIdx.x, h = blockIdx.y, tid = threadIdx.x;
    const int mt64 = mt * 2 + h;
    const int row0 = mt64 * 64;
    #pragma unroll
    for (int i = 0; i < 16; ++i) {
        const int fid = i * 256 + tid;
        const int r = fid >> 6, c4 = fid & 63;
        const float4 v = *reinterpret_cast<const float4*>(
            z + (size_t)(row0 + r) * EDIM + c4 * 4);
        *reinterpret_cast<float4*>(&t[r][c4 * 4]) = v;
    }
    __syncthreads();
    {
        const int r = tid >> 2, q = tid & 3;
        float asum = 0.f;
        for (int c = 0; c < 64; ++c) asum += fabsf(t[r][q * 64 + c]);
        asum += __shfl_xor(asum, 1);
        asum += __shfl_xor(asum, 2);
        #pragma unroll
        for (int cc = 0; cc < 4; ++cc) {
            const int chain = q * 4 + cc;
            const float* x = &t[r][(chain >> 3) * 128];
            const int j = chain & 7;
            float rr = __fmul_rn(x[j], x[j]);
            for (int i = 8; i < 128; i += 8) rr = __fadd_rn(rr, __fmul_rn(x[i + j], x[i + j]));
            ch[r][chain] = rr;
        }
        __syncthreads();
        if (q == 0) {
            const float* c0 = ch[r];
            const float h0 = __fadd_rn(__fadd_rn(__fadd_rn(c0[0], c0[1]), __fadd_rn(c0[2], c0[3])),
                                       __fadd_rn(__fadd_rn(c0[4], c0[5]), __fadd_rn(c0[6], c0[7])));
            const float h1 = __fadd_rn(__fadd_rn(__fadd_rn(c0[8], c0[9]), __fadd_rn(c0[10], c0[11])),
                                       __fadd_rn(__fadd_rn(c0[12], c0[13]), __fadd_rn(c0[14], c0[15])));
            szrow[row0 + r] = __fadd_rn(h0, h1);
            szabs[row0 + r] = asum;
        }
    }
    #pragma unroll
    for (int i = 0; i < 16; ++i) {
        const int sid = i * 256 + tid;
        const int ca = sid >> 8, kgv = (sid >> 6) & 3, rwl = sid & 63;
        const int cbase = ((ca < 8) ? ca : ca - 8) * 32 + kgv * 8;
        u16x8 out;
        #pragma unroll
        for (int j = 0; j < 8; ++j) {
            const float f = t[rwl][cbase + j];
            unsigned short h16 = f32_to_bf16_rne(f);
            if (ca >= 8) h16 = f32_to_bf16_rne(f - bf16_to_f32(h16));
            out[j] = h16;
        }
        char* dst = A2t + ((((size_t)mt64 * 16 + ca) * 256 + (size_t)kgv * 64 + rwl) * 16);
        *reinterpret_cast<u16x8*>(dst) = out;
    }
}

// ---------------- MAIN: 4-way COLUMN split (wave owns 64 rows x 32 entries) ----------------
// Round-14 residual: waves duplicated B reads (2x L2 amplification). Now wc=wid (0..3):
// block reads exactly 8KB B per chunk (1x); B-load instrs halve. A frags fm 0..3 from LDS
// (more ds_reads; LDS BW has headroom). acc[4][2]; top-2 keyed [fm][r]; 4-way merge.
__global__ __launch_bounds__(256, 2)
void vq_main(const char* __restrict__ A2t, const char* __restrict__ B2t,
             const float* __restrict__ cnorm, const float* __restrict__ szrow,
             const float* __restrict__ szabs, const float* __restrict__ emaxp,
             const float* __restrict__ cb,
             float* __restrict__ idxf, int* __restrict__ cnt, int* __restrict__ list,
             float* __restrict__ zq, float* __restrict__ lpart) {
    constexpr int CNS = 65536;
    __shared__ char smem[69632] __attribute__((aligned(16)));   // A 16x4096 @0 ; cns 4KB @65536
    float* cns = reinterpret_cast<float*>(smem + CNS);
    float (*ms1)[4] = reinterpret_cast<float(*)[4]>(smem);      // [64][4], alias A post-loop
    float (*ms2)[4] = reinterpret_cast<float(*)[4]>(smem + 1024);
    int   (*mi1)[4] = reinterpret_cast<int(*)[4]>(smem + 2048);
    int*  bidx      = reinterpret_cast<int*>(smem + 3072);

    const int tid = threadIdx.x;
    const int mtile = blockIdx.x;
    const size_t rowbase = (size_t)mtile * 64;
    const int l = tid & 63, wid = tid >> 6;
    const int kg = l >> 4, li = l & 15;
    const int wc = wid;                       // 4-way column split

    // prologue: cns + all 16 A chunks (64KB) -> LDS, one drain + barrier
    GLL16((const char*)cnorm + tid * 16, smem + CNS + tid * 16);
    const char* Ag = A2t + (size_t)mtile * 65536;
    #pragma unroll
    for (int i = 0; i < 16; ++i)
        GLL16(Ag + (i * 256 + tid) * 16, smem + (i * 256 + tid) * 16);
    asm volatile("s_waitcnt vmcnt(0)" ::: "memory");
    __syncthreads();

    int aoff[4], boff[2];
    #pragma unroll
    for (int f = 0; f < 4; ++f)
        aoff[f] = kg * 1024 + (f * 16 + li) * 16;
    #pragma unroll
    for (int f = 0; f < 2; ++f)
        boff[f] = kg * 2048 + (wc * 32 + f * 16 + li) * 16;

    // prefetch chunk 0 fragments
    bf16x8 cAh[4], cAl[4], cB[2];
    #pragma unroll
    for (int f = 0; f < 4; ++f) {
        cAh[f] = *reinterpret_cast<const bf16x8*>(smem + 0 * 4096 + aoff[f]);
        cAl[f] = *reinterpret_cast<const bf16x8*>(smem + 8 * 4096 + aoff[f]);
    }
    #pragma unroll
    for (int f = 0; f < 2; ++f)
        cB[f] = *reinterpret_cast<const bf16x8*>(B2t + boff[f]);

    float s1v[4][4], s2v[4][4];   // keyed [fm][r] = per row (64 rows = fm*16 + kg*4 + r)
    int i1v[4][4];
    #pragma unroll
    for (int a = 0; a < 4; ++a)
        #pragma unroll
        for (int b = 0; b < 4; ++b) { s1v[a][b] = 3.4e38f; s2v[a][b] = 3.4e38f; i1v[a][b] = 0; }

    for (int nt = 0; nt < 8; ++nt) {
        f32x4 acc[4][2];
        const f32x4 zf4 = {0.f, 0.f, 0.f, 0.f};
        #pragma unroll
        for (int a = 0; a < 4; ++a)
            #pragma unroll
            for (int b = 0; b < 2; ++b) acc[a][b] = zf4;

        #pragma unroll
        for (int j = 0; j < 16; ++j) {
            const int g = nt * 16 + j;
            // prefetch chunk g+1 (g=127 reads 8KB past B2t = szrow region: valid ws, unused)
            bf16x8 nAh[4], nAl[4], nB[2];
            {
                const int jn = (j + 1) & 15;
                const char* gB = B2t + (size_t)(g + 1) * 8192;
                #pragma unroll
                for (int f = 0; f < 2; ++f)
                    nB[f] = *reinterpret_cast<const bf16x8*>(gB + boff[f]);
                if (jn < 8) {
                    #pragma unroll
                    for (int f = 0; f < 4; ++f) {
                        nAh[f] = *reinterpret_cast<const bf16x8*>(smem + jn * 4096 + aoff[f]);
                        nAl[f] = *reinterpret_cast<const bf16x8*>(smem + (8 + jn) * 4096 + aoff[f]);
                    }
                } else {
                    #pragma unroll
                    for (int f = 0; f < 4; ++f) {
                        nAh[f] = *reinterpret_cast<const bf16x8*>(smem + (jn - 8) * 4096 + aoff[f]);
                        nAl[f] = cAl[f];
                    }
                }
            }
            // MFMA chunk g (j<8: hiA*hiB + loA*hiB ; j>=8: hiA*loB)
            #pragma unroll
            for (int fm = 0; fm < 4; ++fm)
                #pragma unroll
                for (int fn = 0; fn < 2; ++fn)
                    acc[fm][fn] = __builtin_amdgcn_mfma_f32_16x16x32_bf16(cAh[fm], cB[fn], acc[fm][fn], 0, 0, 0);
            if (j < 8) {
                #pragma unroll
                for (int fm = 0; fm < 4; ++fm)
                    #pragma unroll
                    for (int fn = 0; fn < 2; ++fn)
                        acc[fm][fn] = __builtin_amdgcn_mfma_f32_16x16x32_bf16(cAl[fm], cB[fn], acc[fm][fn], 0, 0, 0);
            }
            #pragma unroll
            for (int f = 0; f < 4; ++f) { cAh[f] = nAh[f]; cAl[f] = nAl[f]; }
            #pragma unroll
            for (int f = 0; f < 2; ++f) cB[f] = nB[f];
        }

        // per-nt epilogue: score = cn - 2*dot ; top-2 per ROW [fm][r] (e ascending over fn)
        const int ntb = nt * 128;
        #pragma unroll
        for (int fn = 0; fn < 2; ++fn) {
            const int e = ntb + wc * 32 + fn * 16 + li;
            const float cn = cns[e];
            #pragma unroll
            for (int fm = 0; fm < 4; ++fm)
                #pragma unroll
                for (int r = 0; r < 4; ++r) {
                    const float s = cn - 2.0f * acc[fm][fn][r];
                    if (s < s1v[fm][r]) { s2v[fm][r] = s1v[fm][r]; s1v[fm][r] = s; i1v[fm][r] = e; }
                    else s2v[fm][r] = fminf(s2v[fm][r], s);
                }
        }
    }

    __syncthreads();   // all waves done reading A region; merge arrays may alias it

    // stage 1: butterfly over 16 li-lanes (same row, same wc-quarter) -> ms*[row][wc]
    #pragma unroll
    for (int fm = 0; fm < 4; ++fm)
        #pragma unroll
        for (int r = 0; r < 4; ++r) {
            float s1 = s1v[fm][r], s2 = s2v[fm][r];
            int i1 = i1v[fm][r];
            #pragma unroll
            for (int off = 1; off < 16; off <<= 1) {
                const float os1 = __shfl_xor(s1, off);
                const float os2 = __shfl_xor(s2, off);
                const int oi1 = __shfl_xor(i1, off);
                const bool take = (os1 < s1) || (os1 == s1 && oi1 < i1);
                const float loser = take ? s1 : os1;
                if (take) { s1 = os1; i1 = oi1; }
                s2 = fminf(fminf(s2, os2), loser);
            }
            if (li == 0) {
                const int rloc = fm * 16 + (kg << 2) + r;
                ms1[rloc][wc] = s1; ms2[rloc][wc] = s2; mi1[rloc][wc] = i1;
            }
        }
    __syncthreads();

    // stage 2: 4-way quarter merge (disjoint entry sets; tie -> smaller index = np order)
    if (tid < 64) {
        float s1 = ms1[tid][0], s2 = ms2[tid][0];
        int i1 = mi1[tid][0];
        #pragma unroll
        for (int q = 1; q < 4; ++q) {
            const float o1 = ms1[tid][q], o2 = ms2[tid][q];
            const int oi = mi1[tid][q];
            const bool take = (o1 < s1) || (o1 == s1 && oi < i1);
            const float loser = take ? s1 : o1;
            if (take) { s1 = o1; i1 = oi; }
            s2 = fminf(fminf(s2, o2), loser);
        }
        const int rowg = (int)rowbase + tid;
        const float szv = szrow[rowg], sab = szabs[rowg];
        const float M = 2.0e-4f * sab * emaxp[0] + ldexpf(1.0f, ilogbf(szv * 1.02f) - 23);
        idxf[rowg] = (float)i1;
        lpart[rowg] = s1 + szv;
        bidx[tid] = i1;
        if (s2 - s1 <= 2.0f * M) { const int p = atomicAdd(cnt, 1); list[p] = rowg; }
    }
    __syncthreads();

    // fused zq gather: 4 waves x 16 rows, float4 coalesced from L2-hot cb
    {
        const float4* cb4 = reinterpret_cast<const float4*>(cb);
        float4* zq4 = reinterpret_cast<float4*>(zq);
        #pragma unroll 4
        for (int j = 0; j < 16; ++j) {
            const int rr = wid * 16 + j;
            const int e = bidx[rr];
            zq4[(rowbase + rr) * 64 + l] = cb4[(size_t)e * 64 + l];
        }
    }
}

// ---------------- RESCAN: exact np argmin for flagged rows + zq/lpart rewrite ----------------
__global__ __launch_bounds__(256)
void vq_rescan(const float* __restrict__ z, const float* __restrict__ cb,
               const float* __restrict__ cnorm, const float* __restrict__ szrow,
               const int* __restrict__ list, const int* __restrict__ cntp,
               float* __restrict__ idxf, float* __restrict__ zq, float* __restrict__ lpart) {
    __shared__ float zr[8][260];
    __shared__ float szs[8];
    __shared__ int rows_s[8];
    __shared__ float sred[256];
    __shared__ int ired[256];
    const int tid = threadIdx.x;
    const int n = cntp[0];
    const int groups = (n + 7) >> 3;
    for (int g = blockIdx.x; g < groups; g += gridDim.x) {
        if (tid < 8) {
            const int gi = g * 8 + tid;
            const int row = (gi < n) ? list[gi] : -1;
            rows_s[tid] = row;
            szs[tid] = (row >= 0) ? szrow[row] : 0.f;
        }
        __syncthreads();
        #pragma unroll
        for (int i = 0; i < 8; ++i) {
            const int sid = i * 256 + tid;
            const int rr = sid >> 8, k = sid & 255;
            if (rows_s[rr] >= 0) zr[rr][k] = z[(size_t)rows_s[rr] * EDIM + k];
        }
        __syncthreads();
        float bs[8];
        int bi[8];
        #pragma unroll
        for (int rr = 0; rr < 8; ++rr) { bs[rr] = 3.4e38f; bi[rr] = 0; }
        for (int q = 0; q < 4; ++q) {
            const int e = tid + q * 256;
            const float4* crow = reinterpret_cast<const float4*>(cb + (size_t)e * EDIM);
            float d[8];
            #pragma unroll
            for (int rr = 0; rr < 8; ++rr) d[rr] = 0.f;
            for (int k4 = 0; k4 < 64; ++k4) {
                const float4 c4 = crow[k4];
                #pragma unroll
                for (int rr = 0; rr < 8; ++rr) {
                    d[rr] = fmaf(zr[rr][k4 * 4 + 0], c4.x, d[rr]);
                    d[rr] = fmaf(zr[rr][k4 * 4 + 1], c4.y, d[rr]);
                    d[rr] = fmaf(zr[rr][k4 * 4 + 2], c4.z, d[rr]);
                    d[rr] = fmaf(zr[rr][k4 * 4 + 3], c4.w, d[rr]);
                }
            }
            const float cn = cnorm[e];
            #pragma unroll
            for (int rr = 0; rr < 8; ++rr) {
                const float b1 = __fadd_rn(szs[rr], __fmul_rn(-2.0f, d[rr]));
                const float s = __fadd_rn(b1, cn);
                if (s < bs[rr]) { bs[rr] = s; bi[rr] = e; }
            }
        }
        #pragma unroll
        for (int rr = 0; rr < 8; ++rr) {
            sred[tid] = bs[rr];
            ired[tid] = bi[rr];
            __syncthreads();
            for (int h = 128; h; h >>= 1) {
                if (tid < h) {
                    const float so = sred[tid + h];
                    const int io = ired[tid + h];
                    if (so < sred[tid] || (so == sred[tid] && io < ired[tid])) {
                        sred[tid] = so; ired[tid] = io;
                    }
                }
                __syncthreads();
            }
            if (rows_s[rr] >= 0) {
                const int best = ired[0];
                const int row = rows_s[rr];
                zq[(size_t)row * EDIM + tid] = cb[(size_t)best * EDIM + tid];
                if (tid == 0) { idxf[row] = (float)best; lpart[row] = sred[0]; }
            }
            __syncthreads();
        }
    }
}

// ---------------- loss: 2-stage tree ----------------
__global__ void vq_loss1(const float* __restrict__ lpart, float* __restrict__ lp2) {
    __shared__ float red[256];
    const int t = threadIdx.x;
    red[t] = lpart[blockIdx.x * 256 + t];
    __syncthreads();
    for (int h = 128; h; h >>= 1) {
        if (t < h) red[t] += red[t + h];
        __syncthreads();
    }
    if (t == 0) lp2[blockIdx.x] = red[0];
}
__global__ void vq_loss2(const float* __restrict__ lp2, float* __restrict__ outloss) {
    __shared__ float red[256];
    const int t = threadIdx.x;
    red[t] = lp2[t];
    __syncthreads();
    for (int h = 128; h; h >>= 1) {
        if (t < h) red[t] += red[t + h];
        __syncthreads();
    }
    if (t == 0) outloss[0] = red[0] * ((1.0f + BETA) / 16777216.0f);
}

// ================= FALLBACK (round-2, known-passing) =================
__device__ __forceinline__ float np_sum128_sq(const float* __restrict__ x) {
    float r[8];
    #pragma unroll
    for (int j = 0; j < 8; ++j) r[j] = __fmul_rn(x[j], x[j]);
    #pragma unroll
    for (int i = 8; i < 128; i += 8)
        #pragma unroll
        for (int j = 0; j < 8; ++j) r[j] = __fadd_rn(r[j], __fmul_rn(x[i + j], x[i + j]));
    return __fadd_rn(__fadd_rn(__fadd_rn(r[0], r[1]), __fadd_rn(r[2], r[3])),
                     __fadd_rn(__fadd_rn(r[4], r[5]), __fadd_rn(r[6], r[7])));
}
__global__ void fb_prep(const float* __restrict__ z, const float* __restrict__ cb,
                        float* __restrict__ szrow, float* __restrict__ cnorm) {
    int t = blockIdx.x * blockDim.x + threadIdx.x;
    if (t < NROWS) {
        const float* x = z + (size_t)t * EDIM;
        szrow[t] = __fadd_rn(np_sum128_sq(x), np_sum128_sq(x + 128));
    } else if (t < NROWS + NE) {
        const float* x = cb + (size_t)(t - NROWS) * EDIM;
        cnorm[t - NROWS] = __fadd_rn(np_sum128_sq(x), np_sum128_sq(x + 128));
    }
}
__global__ __launch_bounds__(256, 2)
void fb_vq(const float* __restrict__ z, const float* __restrict__ cb,
           const float* __restrict__ cnorm, const float* __restrict__ szrow,
           float* __restrict__ zq, float* __restrict__ idxf, float* __restrict__ lpart) {
    __shared__ float As[64 * 268];
    __shared__ float Bs[32 * 68];
    __shared__ int bidx[64];
    __shared__ float lred[4];
    const int tid = threadIdx.x;
    const int tx = tid & 15, ty = tid >> 4;
    const size_t rowbase = (size_t)blockIdx.x * 64;
    const float4* zg = reinterpret_cast<const float4*>(z + rowbase * EDIM);
    #pragma unroll
    for (int it = 0; it < 16; ++it) {
        int id = it * 256 + tid;
        int r = id >> 6, c4 = id & 63;
        float4 v = zg[id];
        *reinterpret_cast<float4*>(&As[r * 268 + c4 * 4]) = v;
    }
    float sz[4];
    #pragma unroll
    for (int m = 0; m < 4; ++m) sz[m] = szrow[rowbase + ty * 4 + m];
    float bestS[4]; int bestI[4];
    #pragma unroll
    for (int m = 0; m < 4; ++m) { bestS[m] = 3.4e38f; bestI[m] = 0; }
    for (int nt = 0; nt < NE / 64; ++nt) {
        float acc[4][4];
        #pragma unroll
        for (int m = 0; m < 4; ++m)
            #pragma unroll
            for (int n = 0; n < 4; ++n) acc[m][n] = 0.f;
        const int ebase = nt * 64;
        for (int k0 = 0; k0 < EDIM; k0 += 32) {
            __syncthreads();
            #pragma unroll
            for (int i = 0; i < 8; ++i) {
                int id = i * 256 + tid;
                int n = id >> 5, k = id & 31;
                Bs[k * 68 + n] = cb[(size_t)(ebase + n) * EDIM + k0 + k];
            }
            __syncthreads();
            #pragma unroll
            for (int kg2 = 0; kg2 < 32; kg2 += 4) {
                float4 a[4], b[4];
                #pragma unroll
                for (int m = 0; m < 4; ++m)
                    a[m] = *reinterpret_cast<const float4*>(&As[(ty * 4 + m) * 268 + k0 + kg2]);
                #pragma unroll
                for (int kk = 0; kk < 4; ++kk)
                    b[kk] = *reinterpret_cast<const float4*>(&Bs[(kg2 + kk) * 68 + tx * 4]);
                #pragma unroll
                for (int m = 0; m < 4; ++m) {
                    const float* av = reinterpret_cast<const float*>(&a[m]);
                    #pragma unroll
                    for (int kk = 0; kk < 4; ++kk) {
                        acc[m][0] = fmaf(av[kk], b[kk].x, acc[m][0]);
                        acc[m][1] = fmaf(av[kk], b[kk].y, acc[m][1]);
                        acc[m][2] = fmaf(av[kk], b[kk].z, acc[m][2]);
                        acc[m][3] = fmaf(av[kk], b[kk].w, acc[m][3]);
                    }
                }
            }
        }
        #pragma unroll
        for (int n = 0; n < 4; ++n) {
            int e = ebase + tx * 4 + n;
            float cn = cnorm[e];
            #pragma unroll
            for (int m = 0; m < 4; ++m) {
                float b1 = __fadd_rn(sz[m], __fmul_rn(-2.0f, acc[m][n]));
                float s = __fadd_rn(b1, cn);
                if (s < bestS[m]) { bestS[m] = s; bestI[m] = e; }
            }
        }
    }
    #pragma unroll
    for (int m = 0; m < 4; ++m) {
        float s = bestS[m]; int i = bestI[m];
        #pragma unroll
        for (int off = 1; off < 16; off <<= 1) {
            float s2 = __shfl_xor(s, off);
            int i2 = __shfl_xor(i, off);
            if (s2 < s || (s2 == s && i2 < i)) { s = s2; i = i2; }
        }
        if (tx == 0) bidx[ty * 4 + m] = i;
    }
    __syncthreads();
    if (tid < 64) idxf[rowbase + tid] = (float)bidx[tid];
    float lsum = 0.f;
    for (int r = 0; r < 64; ++r) {
        int e = bidx[r];
        float c = cb[(size_t)e * EDIM + tid];
        float zv = As[r * 268 + tid];
        float d = c - zv;
        lsum = fmaf(d, d, lsum);
        zq[(rowbase + r) * EDIM + tid] = c;
    }
    #pragma unroll
    for (int off = 32; off; off >>= 1) lsum += __shfl_down(lsum, off);
    if ((tid & 63) == 0) lred[tid >> 6] = lsum;
    __syncthreads();
    if (tid == 0) lpart[blockIdx.x] = lred[0] + lred[1] + lred[2] + lred[3];
}
__global__ void fb_loss(const float* __restrict__ lpart, float* __restrict__ out_loss) {
    __shared__ float red[256];
    int tid = threadIdx.x;
    float s = 0.f;
    for (int i = tid; i < NROWS / 64; i += 256) s += lpart[i];
    red[tid] = s;
    __syncthreads();
    for (int h = 128; h; h >>= 1) {
        if (tid < h) red[tid] += red[tid + h];
        __syncthreads();
    }
    if (tid == 0) out_loss[0] = red[0] * (1.0f + BETA) / (float)((size_t)NROWS * EDIM);
}

// ================= launch =================
extern "C" void kernel_launch(void* const* d_in, const int* in_sizes, int n_in,
                              void* d_out, int out_size, void* d_ws, size_t ws_size,
                              hipStream_t stream) {
    const float* z = (const float*)d_in[0];
    const float* cb = (const float*)d_in[1];
    float* out = (float*)d_out;
    float* zq = out;
    float* loss = out + (size_t)NROWS * EDIM;
    float* idxf = loss + 1;
    char* ws = (char*)d_ws;

    if (ws_size < WS_NEED) {  // fallback: round-2 path (known passing, ~789us)
        float* cnorm = (float*)ws;
        float* szrow = cnorm + NE;
        float* lpart = szrow + NROWS;
        hipLaunchKernelGGL(fb_prep, dim3((NROWS + NE + 255) / 256), dim3(256), 0, stream, z, cb, szrow, cnorm);
        hipLaunchKernelGGL(fb_vq, dim3(NROWS / 64), dim3(256), 0, stream, z, cb, cnorm, szrow, zq, idxf, lpart);
        hipLaunchKernelGGL(fb_loss, dim3(1), dim3(256), 0, stream, lpart, loss);
        return;
    }

    char* A2t = ws + A2T_OFF;
    char* B2t = ws + B2T_OFF;
    float* szrow = (float*)(ws + SZROW_OFF);
    float* szabs = (float*)(ws + SZABS_OFF);
    float* cnorm = (float*)(ws + CNORM_OFF);
    float* emax = (float*)(ws + EMAX_OFF);
    int* cnt = (int*)(ws + CNT_OFF);
    int* list = (int*)(ws + LIST_OFF);
    float* lpart = (float*)(ws + LPART_OFF);
    float* lp2 = (float*)(ws + LP2_OFF);

    hipMemsetAsync(emax, 0, 4, stream);   // 0u == 0.0f: atomicMax identity for amax >= 0
    hipMemsetAsync(cnt, 0, 4, stream);
    hipLaunchKernelGGL(p3_codebook, dim3(NE), dim3(64), 0, stream, cb, cnorm, B2t, (unsigned*)emax);
    hipLaunchKernelGGL(p2_atile, dim3(512, 2), dim3(256), 0, stream, z, A2t, szrow, szabs);
    hipLaunchKernelGGL(vq_main, dim3(1024), dim3(256), 0, stream,
                       A2t, B2t, cnorm, szrow, szabs, emax, cb, idxf, cnt, list, zq, lpart);
    hipLaunchKernelGGL(vq_rescan, dim3(1024), dim3(256), 0, stream,
                       z, cb, cnorm, szrow, list, cnt, idxf, zq, lpart);
    hipLaunchKernelGGL(vq_loss1, dim3(256), dim3(256), 0, stream, lpart, lp2);
    hipLaunchKernelGGL(vq_loss2, dim3(1), dim3(256), 0, stream, lp2, loss);
}

// Round 16
// 237.106 us; speedup vs baseline: 1.6134x; 1.6134x over previous
//
#include <hip/hip_runtime.h>
#include <hip/hip_bf16.h>
#include <math.h>

typedef __bf16 bf16x8 __attribute__((ext_vector_type(8)));
typedef float f32x4 __attribute__((ext_vector_type(4)));
typedef unsigned short u16x8 __attribute__((ext_vector_type(8)));

constexpr int EDIM = 256;
constexpr int NE = 1024;
constexpr int NROWS = 65536;
constexpr float BETA = 0.25f;

// ---------------- ws layout (bytes) ----------------
constexpr size_t B2T_OFF   = 0;                          // [128 chunk][8192B]: per nt 16 (8 hi + 8 lo)
constexpr size_t B2T_SZ    = (size_t)8 * 16 * 8192;      // 1 MB
constexpr size_t SZROW_OFF = B2T_OFF + B2T_SZ;           // 65536 f32 (also absorbs g=128 dummy prefetch)
constexpr size_t SZABS_OFF = SZROW_OFF + 262144;         // 65536 f32
constexpr size_t CNORM_OFF = SZABS_OFF + 262144;         // 1024 f32
constexpr size_t EMAX_OFF  = CNORM_OFF + 4096;           // 1 f32 (atomicMax target)
constexpr size_t CNT_OFF   = EMAX_OFF + 256;             // 1 i32
constexpr size_t LIST_OFF  = CNT_OFF + 256;              // 65536 i32
constexpr size_t LPART_OFF = LIST_OFF + 262144;          // 65536 f32
constexpr size_t LP2_OFF   = LPART_OFF + 262144;         // 256 f32
constexpr size_t WS_NEED   = LP2_OFF + 1024;             // ~2.6 MB

__device__ __forceinline__ unsigned short f32_to_bf16_rne(float f) {
    unsigned u = __float_as_uint(f);
    u += 0x7fffu + ((u >> 16) & 1u);
    return (unsigned short)(u >> 16);
}
__device__ __forceinline__ float bf16_to_f32(unsigned short h) {
    return __uint_as_float((unsigned)h << 16);
}

#define GLL16(g, l)                                                                   \
    __builtin_amdgcn_global_load_lds(                                                 \
        (const __attribute__((address_space(1))) unsigned int*)(g),                   \
        (__attribute__((address_space(3))) unsigned int*)(l), 16, 0, 0)

// ---------------- P3: codebook: cnorm exact, hi/lo bf16 -> B2t, atomicMax |e| ----------------
__global__ __launch_bounds__(64)
void p3_codebook(const float* __restrict__ cb, float* __restrict__ cnorm,
                 char* __restrict__ B2t, unsigned* __restrict__ emax_u) {
    __shared__ float xr[256];
    __shared__ float rres[16];
    __shared__ unsigned short ehi[256], elo[256];
    const int e = blockIdx.x, l = threadIdx.x;
    const float4 v = reinterpret_cast<const float4*>(cb + (size_t)e * EDIM)[l];
    *reinterpret_cast<float4*>(&xr[l * 4]) = v;
    float amax = fmaxf(fmaxf(fabsf(v.x), fabsf(v.y)), fmaxf(fabsf(v.z), fabsf(v.w)));
    #pragma unroll
    for (int off = 32; off; off >>= 1) amax = fmaxf(amax, __shfl_down(amax, off));
    __syncthreads();
    #pragma unroll
    for (int i = 0; i < 4; ++i) {
        const int idx = i * 64 + l;
        const float f = xr[idx];
        const unsigned short h = f32_to_bf16_rne(f);
        ehi[idx] = h;
        elo[idx] = f32_to_bf16_rne(f - bf16_to_f32(h));
    }
    if (l < 16) {
        const float* x = xr + (l >> 3) * 128;
        const int j = l & 7;
        float r = __fmul_rn(x[j], x[j]);
        for (int i = 8; i < 128; i += 8) r = __fadd_rn(r, __fmul_rn(x[i + j], x[i + j]));
        rres[l] = r;
    }
    __syncthreads();
    if (l == 0) {
        float h0 = __fadd_rn(__fadd_rn(__fadd_rn(rres[0], rres[1]), __fadd_rn(rres[2], rres[3])),
                             __fadd_rn(__fadd_rn(rres[4], rres[5]), __fadd_rn(rres[6], rres[7])));
        float h1 = __fadd_rn(__fadd_rn(__fadd_rn(rres[8], rres[9]), __fadd_rn(rres[10], rres[11])),
                             __fadd_rn(__fadd_rn(rres[12], rres[13]), __fadd_rn(rres[14], rres[15])));
        cnorm[e] = __fadd_rn(h0, h1);
        atomicMax(emax_u, __float_as_uint(amax));   // amax >= 0: bit-order == float-order
    }
    // B2t: global chunk g = (e>>7)*16 + c ; c 0-7 = ehi k-block c, c 8-15 = elo k-block c-8
    {
        const int c = l >> 2, kgv = l & 3;   // 64 slots exactly
        const int colbase = ((c < 8) ? c * 32 : (c - 8) * 32) + kgv * 8;
        const unsigned short* src = (c < 8) ? ehi : elo;
        char* dst = B2t + ((((size_t)(e >> 7) * 16 + c) * 512 + (size_t)kgv * 128 + (e & 127)) * 16);
        *reinterpret_cast<uint4*>(dst) = *reinterpret_cast<const uint4*>(&src[colbase]);
    }
}

// ---------------- MAIN: fused z->bf16 conversion + stats + round-14 K-loop ----------------
// LDS (71680): prologue: t[64][260] f32 @0 (66560B) | ch[64][16] @66560 | szs @70656.
// steady: A tiles 16x4096 @0 | cns 4KB @65536 | szs @70656 ; merge arrays alias @0.
// K-loop is byte-identical to round 14 (proven 150us, arch-VGPR <= 128, no spill):
// wave (wr=wid>>1, wc=wid&1) owns 32 rows x 64 entries, acc[2][4], B global->reg.
__global__ __launch_bounds__(256, 2)
void vq_main(const float* __restrict__ z, const char* __restrict__ B2t,
             const float* __restrict__ cnorm, const float* __restrict__ emaxp,
             const float* __restrict__ cb,
             float* __restrict__ idxf, int* __restrict__ cnt, int* __restrict__ list,
             float* __restrict__ zq, float* __restrict__ lpart,
             float* __restrict__ szrow, float* __restrict__ szabs) {
    constexpr int CNS = 65536;
    __shared__ char smem[71680] __attribute__((aligned(16)));
    float* cns  = reinterpret_cast<float*>(smem + CNS);
    float* szsr = reinterpret_cast<float*>(smem + 70656);   // [64]
    float* szsa = reinterpret_cast<float*>(smem + 70912);   // [64]
    float (*ms1)[2] = reinterpret_cast<float(*)[2]>(smem);  // [64][2], alias A post-loop
    float (*ms2)[2] = reinterpret_cast<float(*)[2]>(smem + 512);
    int   (*mi1)[2] = reinterpret_cast<int(*)[2]>(smem + 1024);
    int*  bidx      = reinterpret_cast<int*>(smem + 1536);

    const int tid = threadIdx.x;
    const int mtile = blockIdx.x;
    const size_t rowbase = (size_t)mtile * 64;
    const int l = tid & 63, wid = tid >> 6;
    const int kg = l >> 4, li = l & 15;
    const int wr = wid >> 1, wc = wid & 1;

    // ---- prologue phase 0: z -> LDS f32 tile [64][260], coalesced float4 ----
    {
        float* t = reinterpret_cast<float*>(smem);
        #pragma unroll
        for (int i = 0; i < 16; ++i) {
            const int fid = i * 256 + tid;
            const int r = fid >> 6, c4 = fid & 63;
            const float4 v = *reinterpret_cast<const float4*>(
                z + (rowbase + r) * EDIM + c4 * 4);
            *reinterpret_cast<float4*>(&t[r * 260 + c4 * 4]) = v;
        }
    }
    __syncthreads();
    // ---- phase 1: stats (p2's np-bitwise chain code verbatim; ch in dead-LDS scratch) ----
    {
        float* t = reinterpret_cast<float*>(smem);
        float (*ch)[16] = reinterpret_cast<float(*)[16]>(smem + 66560);
        const int r = tid >> 2, q = tid & 3;
        float asum = 0.f;
        for (int c = 0; c < 64; ++c) asum += fabsf(t[r * 260 + q * 64 + c]);
        asum += __shfl_xor(asum, 1);
        asum += __shfl_xor(asum, 2);
        #pragma unroll
        for (int cc = 0; cc < 4; ++cc) {
            const int chain = q * 4 + cc;
            const float* x = &t[r * 260 + (chain >> 3) * 128];
            const int j = chain & 7;
            float rr = __fmul_rn(x[j], x[j]);
            for (int i = 8; i < 128; i += 8) rr = __fadd_rn(rr, __fmul_rn(x[i + j], x[i + j]));
            ch[r][chain] = rr;
        }
        __syncthreads();
        if (q == 0) {
            const float* c0 = ch[r];
            const float h0 = __fadd_rn(__fadd_rn(__fadd_rn(c0[0], c0[1]), __fadd_rn(c0[2], c0[3])),
                                       __fadd_rn(__fadd_rn(c0[4], c0[5]), __fadd_rn(c0[6], c0[7])));
            const float h1 = __fadd_rn(__fadd_rn(__fadd_rn(c0[8], c0[9]), __fadd_rn(c0[10], c0[11])),
                                       __fadd_rn(__fadd_rn(c0[12], c0[13]), __fadd_rn(c0[14], c0[15])));
            const float sz = __fadd_rn(h0, h1);
            szsr[r] = sz; szsa[r] = asum;
            szrow[rowbase + r] = sz;                 // global: consumed by rescan
            szabs[rowbase + r] = asum;
        }
    }
    // ---- phase 2: convert this thread's 64 floats (row r, cols q*64..+63) to bf16 hi/lo regs ----
    u16x8 chi[8], clo[8];
    {
        float* t = reinterpret_cast<float*>(smem);
        const int r = tid >> 2, q = tid & 3;
        #pragma unroll
        for (int s = 0; s < 8; ++s) {
            u16x8 h, lw;
            #pragma unroll
            for (int j = 0; j < 8; ++j) {
                const float f = t[r * 260 + q * 64 + s * 8 + j];
                const unsigned short hh = f32_to_bf16_rne(f);
                h[j] = hh;
                lw[j] = f32_to_bf16_rne(f - bf16_to_f32(hh));
            }
            chi[s] = h; clo[s] = lw;
        }
    }
    __syncthreads();   // all f32 reads done before in-place overwrite
    // ---- phase 3: ds_write A tiles (EXACT round-14 layout: chunk ca @ ca*4096, (kgv*64+row)*16) ----
    {
        const int r = tid >> 2, q = tid & 3;
        #pragma unroll
        for (int s = 0; s < 8; ++s) {
            const int ca = 2 * q + (s >> 2), kgv = s & 3;
            *reinterpret_cast<u16x8*>(smem + (ca * 256 + kgv * 64 + r) * 16) = chi[s];
            *reinterpret_cast<u16x8*>(smem + ((8 + ca) * 256 + kgv * 64 + r) * 16) = clo[s];
        }
    }
    // ---- phase 4: cns -> LDS (ch scratch dead now), drain, barrier ----
    GLL16((const char*)cnorm + tid * 16, smem + CNS + tid * 16);
    asm volatile("s_waitcnt vmcnt(0)" ::: "memory");
    __syncthreads();

    // ================= K-loop: byte-identical to round 14 =================
    int aoff[2], boff[4];
    #pragma unroll
    for (int f = 0; f < 2; ++f)
        aoff[f] = kg * 1024 + (wr * 32 + f * 16 + li) * 16;
    #pragma unroll
    for (int f = 0; f < 4; ++f)
        boff[f] = kg * 2048 + (wc * 64 + f * 16 + li) * 16;

    bf16x8 cAh[2], cAl[2], cB[4];
    #pragma unroll
    for (int f = 0; f < 2; ++f) {
        cAh[f] = *reinterpret_cast<const bf16x8*>(smem + 0 * 4096 + aoff[f]);
        cAl[f] = *reinterpret_cast<const bf16x8*>(smem + 8 * 4096 + aoff[f]);
    }
    #pragma unroll
    for (int f = 0; f < 4; ++f)
        cB[f] = *reinterpret_cast<const bf16x8*>(B2t + boff[f]);

    float s1v[2][4], s2v[2][4];   // keyed [fm][r] = per row
    int i1v[2][4];
    #pragma unroll
    for (int a = 0; a < 2; ++a)
        #pragma unroll
        for (int b = 0; b < 4; ++b) { s1v[a][b] = 3.4e38f; s2v[a][b] = 3.4e38f; i1v[a][b] = 0; }

    for (int nt = 0; nt < 8; ++nt) {
        f32x4 acc[2][4];
        const f32x4 zf4 = {0.f, 0.f, 0.f, 0.f};
        #pragma unroll
        for (int a = 0; a < 2; ++a)
            #pragma unroll
            for (int b = 0; b < 4; ++b) acc[a][b] = zf4;

        #pragma unroll
        for (int j = 0; j < 16; ++j) {
            const int g = nt * 16 + j;
            // prefetch chunk g+1 (g=127 reads 8KB past B2t = szrow region: valid ws, unused)
            bf16x8 nAh[2], nAl[2], nB[4];
            {
                const int jn = (j + 1) & 15;
                const char* gB = B2t + (size_t)(g + 1) * 8192;
                #pragma unroll
                for (int f = 0; f < 4; ++f)
                    nB[f] = *reinterpret_cast<const bf16x8*>(gB + boff[f]);
                if (jn < 8) {
                    #pragma unroll
                    for (int f = 0; f < 2; ++f) {
                        nAh[f] = *reinterpret_cast<const bf16x8*>(smem + jn * 4096 + aoff[f]);
                        nAl[f] = *reinterpret_cast<const bf16x8*>(smem + (8 + jn) * 4096 + aoff[f]);
                    }
                } else {
                    #pragma unroll
                    for (int f = 0; f < 2; ++f) {
                        nAh[f] = *reinterpret_cast<const bf16x8*>(smem + (jn - 8) * 4096 + aoff[f]);
                        nAl[f] = cAl[f];
                    }
                }
            }
            // MFMA chunk g (j<8: hiA*hiB + loA*hiB ; j>=8: hiA*loB)
            #pragma unroll
            for (int fm = 0; fm < 2; ++fm)
                #pragma unroll
                for (int fn = 0; fn < 4; ++fn)
                    acc[fm][fn] = __builtin_amdgcn_mfma_f32_16x16x32_bf16(cAh[fm], cB[fn], acc[fm][fn], 0, 0, 0);
            if (j < 8) {
                #pragma unroll
                for (int fm = 0; fm < 2; ++fm)
                    #pragma unroll
                    for (int fn = 0; fn < 4; ++fn)
                        acc[fm][fn] = __builtin_amdgcn_mfma_f32_16x16x32_bf16(cAl[fm], cB[fn], acc[fm][fn], 0, 0, 0);
            }
            #pragma unroll
            for (int f = 0; f < 2; ++f) { cAh[f] = nAh[f]; cAl[f] = nAl[f]; }
            #pragma unroll
            for (int f = 0; f < 4; ++f) cB[f] = nB[f];
        }

        // per-nt epilogue: score = cn - 2*dot ; top-2 per ROW [fm][r] (e ascending over fn)
        const int ntb = nt * 128;
        #pragma unroll
        for (int fn = 0; fn < 4; ++fn) {
            const int e = ntb + wc * 64 + fn * 16 + li;
            const float cn = cns[e];
            #pragma unroll
            for (int fm = 0; fm < 2; ++fm)
                #pragma unroll
                for (int r = 0; r < 4; ++r) {
                    const float s = cn - 2.0f * acc[fm][fn][r];
                    if (s < s1v[fm][r]) { s2v[fm][r] = s1v[fm][r]; s1v[fm][r] = s; i1v[fm][r] = e; }
                    else s2v[fm][r] = fminf(s2v[fm][r], s);
                }
        }
    }

    __syncthreads();   // all waves done reading A region; merge arrays may alias it

    // stage 1: butterfly over 16 li-lanes (same row, same wc-half) -> ms*[row][wc]
    #pragma unroll
    for (int fm = 0; fm < 2; ++fm)
        #pragma unroll
        for (int r = 0; r < 4; ++r) {
            float s1 = s1v[fm][r], s2 = s2v[fm][r];
            int i1 = i1v[fm][r];
            #pragma unroll
            for (int off = 1; off < 16; off <<= 1) {
                const float os1 = __shfl_xor(s1, off);
                const float os2 = __shfl_xor(s2, off);
                const int oi1 = __shfl_xor(i1, off);
                const bool take = (os1 < s1) || (os1 == s1 && oi1 < i1);
                const float loser = take ? s1 : os1;
                if (take) { s1 = os1; i1 = oi1; }
                s2 = fminf(fminf(s2, os2), loser);
            }
            if (li == 0) {
                const int rloc = wr * 32 + fm * 16 + (kg << 2) + r;
                ms1[rloc][wc] = s1; ms2[rloc][wc] = s2; mi1[rloc][wc] = i1;
            }
        }
    __syncthreads();

    // stage 2: merge wc-halves (disjoint entry sets; tie -> smaller index = np order)
    if (tid < 64) {
        const float a1 = ms1[tid][0], b1 = ms1[tid][1];
        const float a2 = ms2[tid][0], b2 = ms2[tid][1];
        const int ai = mi1[tid][0], bi = mi1[tid][1];
        const bool take = (b1 < a1) || (b1 == a1 && bi < ai);
        const float s1 = take ? b1 : a1;
        const int i1 = take ? bi : ai;
        const float loser = take ? a1 : b1;
        const float s2 = fminf(fminf(a2, b2), loser);
        const int rowg = (int)rowbase + tid;
        const float szv = szsr[tid], sab = szsa[tid];
        const float M = 2.0e-4f * sab * emaxp[0] + ldexpf(1.0f, ilogbf(szv * 1.02f) - 23);
        idxf[rowg] = (float)i1;
        lpart[rowg] = s1 + szv;
        bidx[tid] = i1;
        if (s2 - s1 <= 2.0f * M) { const int p = atomicAdd(cnt, 1); list[p] = rowg; }
    }
    __syncthreads();

    // fused zq gather: 4 waves x 16 rows, float4 coalesced from L2-hot cb
    {
        const float4* cb4 = reinterpret_cast<const float4*>(cb);
        float4* zq4 = reinterpret_cast<float4*>(zq);
        #pragma unroll 4
        for (int j = 0; j < 16; ++j) {
            const int rr = wid * 16 + j;
            const int e = bidx[rr];
            zq4[(rowbase + rr) * 64 + l] = cb4[(size_t)e * 64 + l];
        }
    }
}

// ---------------- RESCAN: exact np argmin for flagged rows + zq/lpart rewrite ----------------
__global__ __launch_bounds__(256)
void vq_rescan(const float* __restrict__ z, const float* __restrict__ cb,
               const float* __restrict__ cnorm, const float* __restrict__ szrow,
               const int* __restrict__ list, const int* __restrict__ cntp,
               float* __restrict__ idxf, float* __restrict__ zq, float* __restrict__ lpart) {
    __shared__ float zr[8][260];
    __shared__ float szs[8];
    __shared__ int rows_s[8];
    __shared__ float sred[256];
    __shared__ int ired[256];
    const int tid = threadIdx.x;
    const int n = cntp[0];
    const int groups = (n + 7) >> 3;
    for (int g = blockIdx.x; g < groups; g += gridDim.x) {
        if (tid < 8) {
            const int gi = g * 8 + tid;
            const int row = (gi < n) ? list[gi] : -1;
            rows_s[tid] = row;
            szs[tid] = (row >= 0) ? szrow[row] : 0.f;
        }
        __syncthreads();
        #pragma unroll
        for (int i = 0; i < 8; ++i) {
            const int sid = i * 256 + tid;
            const int rr = sid >> 8, k = sid & 255;
            if (rows_s[rr] >= 0) zr[rr][k] = z[(size_t)rows_s[rr] * EDIM + k];
        }
        __syncthreads();
        float bs[8];
        int bi[8];
        #pragma unroll
        for (int rr = 0; rr < 8; ++rr) { bs[rr] = 3.4e38f; bi[rr] = 0; }
        for (int q = 0; q < 4; ++q) {
            const int e = tid + q * 256;
            const float4* crow = reinterpret_cast<const float4*>(cb + (size_t)e * EDIM);
            float d[8];
            #pragma unroll
            for (int rr = 0; rr < 8; ++rr) d[rr] = 0.f;
            for (int k4 = 0; k4 < 64; ++k4) {
                const float4 c4 = crow[k4];
                #pragma unroll
                for (int rr = 0; rr < 8; ++rr) {
                    d[rr] = fmaf(zr[rr][k4 * 4 + 0], c4.x, d[rr]);
                    d[rr] = fmaf(zr[rr][k4 * 4 + 1], c4.y, d[rr]);
                    d[rr] = fmaf(zr[rr][k4 * 4 + 2], c4.z, d[rr]);
                    d[rr] = fmaf(zr[rr][k4 * 4 + 3], c4.w, d[rr]);
                }
            }
            const float cn = cnorm[e];
            #pragma unroll
            for (int rr = 0; rr < 8; ++rr) {
                const float b1 = __fadd_rn(szs[rr], __fmul_rn(-2.0f, d[rr]));
                const float s = __fadd_rn(b1, cn);
                if (s < bs[rr]) { bs[rr] = s; bi[rr] = e; }
            }
        }
        #pragma unroll
        for (int rr = 0; rr < 8; ++rr) {
            sred[tid] = bs[rr];
            ired[tid] = bi[rr];
            __syncthreads();
            for (int h = 128; h; h >>= 1) {
                if (tid < h) {
                    const float so = sred[tid + h];
                    const int io = ired[tid + h];
                    if (so < sred[tid] || (so == sred[tid] && io < ired[tid])) {
                        sred[tid] = so; ired[tid] = io;
                    }
                }
                __syncthreads();
            }
            if (rows_s[rr] >= 0) {
                const int best = ired[0];
                const int row = rows_s[rr];
                zq[(size_t)row * EDIM + tid] = cb[(size_t)best * EDIM + tid];
                if (tid == 0) { idxf[row] = (float)best; lpart[row] = sred[0]; }
            }
            __syncthreads();
        }
    }
}

// ---------------- loss: 2-stage tree ----------------
__global__ void vq_loss1(const float* __restrict__ lpart, float* __restrict__ lp2) {
    __shared__ float red[256];
    const int t = threadIdx.x;
    red[t] = lpart[blockIdx.x * 256 + t];
    __syncthreads();
    for (int h = 128; h; h >>= 1) {
        if (t < h) red[t] += red[t + h];
        __syncthreads();
    }
    if (t == 0) lp2[blockIdx.x] = red[0];
}
__global__ void vq_loss2(const float* __restrict__ lp2, float* __restrict__ outloss) {
    __shared__ float red[256];
    const int t = threadIdx.x;
    red[t] = lp2[t];
    __syncthreads();
    for (int h = 128; h; h >>= 1) {
        if (t < h) red[t] += red[t + h];
        __syncthreads();
    }
    if (t == 0) outloss[0] = red[0] * ((1.0f + BETA) / 16777216.0f);
}

// ================= FALLBACK (round-2, known-passing) =================
__device__ __forceinline__ float np_sum128_sq(const float* __restrict__ x) {
    float r[8];
    #pragma unroll
    for (int j = 0; j < 8; ++j) r[j] = __fmul_rn(x[j], x[j]);
    #pragma unroll
    for (int i = 8; i < 128; i += 8)
        #pragma unroll
        for (int j = 0; j < 8; ++j) r[j] = __fadd_rn(r[j], __fmul_rn(x[i + j], x[i + j]));
    return __fadd_rn(__fadd_rn(__fadd_rn(r[0], r[1]), __fadd_rn(r[2], r[3])),
                     __fadd_rn(__fadd_rn(r[4], r[5]), __fadd_rn(r[6], r[7])));
}
__global__ void fb_prep(const float* __restrict__ z, const float* __restrict__ cb,
                        float* __restrict__ szrow, float* __restrict__ cnorm) {
    int t = blockIdx.x * blockDim.x + threadIdx.x;
    if (t < NROWS) {
        const float* x = z + (size_t)t * EDIM;
        szrow[t] = __fadd_rn(np_sum128_sq(x), np_sum128_sq(x + 128));
    } else if (t < NROWS + NE) {
        const float* x = cb + (size_t)(t - NROWS) * EDIM;
        cnorm[t - NROWS] = __fadd_rn(np_sum128_sq(x), np_sum128_sq(x + 128));
    }
}
__global__ __launch_bounds__(256, 2)
void fb_vq(const float* __restrict__ z, const float* __restrict__ cb,
           const float* __restrict__ cnorm, const float* __restrict__ szrow,
           float* __restrict__ zq, float* __restrict__ idxf, float* __restrict__ lpart) {
    __shared__ float As[64 * 268];
    __shared__ float Bs[32 * 68];
    __shared__ int bidx[64];
    __shared__ float lred[4];
    const int tid = threadIdx.x;
    const int tx = tid & 15, ty = tid >> 4;
    const size_t rowbase = (size_t)blockIdx.x * 64;
    const float4* zg = reinterpret_cast<const float4*>(z + rowbase * EDIM);
    #pragma unroll
    for (int it = 0; it < 16; ++it) {
        int id = it * 256 + tid;
        int r = id >> 6, c4 = id & 63;
        float4 v = zg[id];
        *reinterpret_cast<float4*>(&As[r * 268 + c4 * 4]) = v;
    }
    float sz[4];
    #pragma unroll
    for (int m = 0; m < 4; ++m) sz[m] = szrow[rowbase + ty * 4 + m];
    float bestS[4]; int bestI[4];
    #pragma unroll
    for (int m = 0; m < 4; ++m) { bestS[m] = 3.4e38f; bestI[m] = 0; }
    for (int nt = 0; nt < NE / 64; ++nt) {
        float acc[4][4];
        #pragma unroll
        for (int m = 0; m < 4; ++m)
            #pragma unroll
            for (int n = 0; n < 4; ++n) acc[m][n] = 0.f;
        const int ebase = nt * 64;
        for (int k0 = 0; k0 < EDIM; k0 += 32) {
            __syncthreads();
            #pragma unroll
            for (int i = 0; i < 8; ++i) {
                int id = i * 256 + tid;
                int n = id >> 5, k = id & 31;
                Bs[k * 68 + n] = cb[(size_t)(ebase + n) * EDIM + k0 + k];
            }
            __syncthreads();
            #pragma unroll
            for (int kg2 = 0; kg2 < 32; kg2 += 4) {
                float4 a[4], b[4];
                #pragma unroll
                for (int m = 0; m < 4; ++m)
                    a[m] = *reinterpret_cast<const float4*>(&As[(ty * 4 + m) * 268 + k0 + kg2]);
                #pragma unroll
                for (int kk = 0; kk < 4; ++kk)
                    b[kk] = *reinterpret_cast<const float4*>(&Bs[(kg2 + kk) * 68 + tx * 4]);
                #pragma unroll
                for (int m = 0; m < 4; ++m) {
                    const float* av = reinterpret_cast<const float*>(&a[m]);
                    #pragma unroll
                    for (int kk = 0; kk < 4; ++kk) {
                        acc[m][0] = fmaf(av[kk], b[kk].x, acc[m][0]);
                        acc[m][1] = fmaf(av[kk], b[kk].y, acc[m][1]);
                        acc[m][2] = fmaf(av[kk], b[kk].z, acc[m][2]);
                        acc[m][3] = fmaf(av[kk], b[kk].w, acc[m][3]);
                    }
                }
            }
        }
        #pragma unroll
        for (int n = 0; n < 4; ++n) {
            int e = ebase + tx * 4 + n;
            float cn = cnorm[e];
            #pragma unroll
            for (int m = 0; m < 4; ++m) {
                float b1 = __fadd_rn(sz[m], __fmul_rn(-2.0f, acc[m][n]));
                float s = __fadd_rn(b1, cn);
                if (s < bestS[m]) { bestS[m] = s; bestI[m] = e; }
            }
        }
    }
    #pragma unroll
    for (int m = 0; m < 4; ++m) {
        float s = bestS[m]; int i = bestI[m];
        #pragma unroll
        for (int off = 1; off < 16; off <<= 1) {
            float s2 = __shfl_xor(s, off);
            int i2 = __shfl_xor(i, off);
            if (s2 < s || (s2 == s && i2 < i)) { s = s2; i = i2; }
        }
        if (tx == 0) bidx[ty * 4 + m] = i;
    }
    __syncthreads();
    if (tid < 64) idxf[rowbase + tid] = (float)bidx[tid];
    float lsum = 0.f;
    for (int r = 0; r < 64; ++r) {
        int e = bidx[r];
        float c = cb[(size_t)e * EDIM + tid];
        float zv = As[r * 268 + tid];
        float d = c - zv;
        lsum = fmaf(d, d, lsum);
        zq[(rowbase + r) * EDIM + tid] = c;
    }
    #pragma unroll
    for (int off = 32; off; off >>= 1) lsum += __shfl_down(lsum, off);
    if ((tid & 63) == 0) lred[tid >> 6] = lsum;
    __syncthreads();
    if (tid == 0) lpart[blockIdx.x] = lred[0] + lred[1] + lred[2] + lred[3];
}
__global__ void fb_loss(const float* __restrict__ lpart, float* __restrict__ out_loss) {
    __shared__ float red[256];
    int tid = threadIdx.x;
    float s = 0.f;
    for (int i = tid; i < NROWS / 64; i += 256) s += lpart[i];
    red[tid] = s;
    __syncthreads();
    for (int h = 128; h; h >>= 1) {
        if (tid < h) red[tid] += red[tid + h];
        __syncthreads();
    }
    if (tid == 0) out_loss[0] = red[0] * (1.0f + BETA) / (float)((size_t)NROWS * EDIM);
}

// ================= launch =================
extern "C" void kernel_launch(void* const* d_in, const int* in_sizes, int n_in,
                              void* d_out, int out_size, void* d_ws, size_t ws_size,
                              hipStream_t stream) {
    const float* z = (const float*)d_in[0];
    const float* cb = (const float*)d_in[1];
    float* out = (float*)d_out;
    float* zq = out;
    float* loss = out + (size_t)NROWS * EDIM;
    float* idxf = loss + 1;
    char* ws = (char*)d_ws;

    if (ws_size < WS_NEED) {  // fallback: round-2 path (known passing, ~789us)
        float* cnorm = (float*)ws;
        float* szrow = cnorm + NE;
        float* lpart = szrow + NROWS;
        hipLaunchKernelGGL(fb_prep, dim3((NROWS + NE + 255) / 256), dim3(256), 0, stream, z, cb, szrow, cnorm);
        hipLaunchKernelGGL(fb_vq, dim3(NROWS / 64), dim3(256), 0, stream, z, cb, cnorm, szrow, zq, idxf, lpart);
        hipLaunchKernelGGL(fb_loss, dim3(1), dim3(256), 0, stream, lpart, loss);
        return;
    }

    char* B2t = ws + B2T_OFF;
    float* szrow = (float*)(ws + SZROW_OFF);
    float* szabs = (float*)(ws + SZABS_OFF);
    float* cnorm = (float*)(ws + CNORM_OFF);
    float* emax = (float*)(ws + EMAX_OFF);
    int* cnt = (int*)(ws + CNT_OFF);
    int* list = (int*)(ws + LIST_OFF);
    float* lpart = (float*)(ws + LPART_OFF);
    float* lp2 = (float*)(ws + LP2_OFF);

    hipMemsetAsync(emax, 0, 4, stream);   // 0u == 0.0f: atomicMax identity for amax >= 0
    hipMemsetAsync(cnt, 0, 4, stream);
    hipLaunchKernelGGL(p3_codebook, dim3(NE), dim3(64), 0, stream, cb, cnorm, B2t, (unsigned*)emax);
    hipLaunchKernelGGL(vq_main, dim3(1024), dim3(256), 0, stream,
                       z, B2t, cnorm, emax, cb, idxf, cnt, list, zq, lpart, szrow, szabs);
    hipLaunchKernelGGL(vq_rescan, dim3(1024), dim3(256), 0, stream,
                       z, cb, cnorm, szrow, list, cnt, idxf, zq, lpart);
    hipLaunchKernelGGL(vq_loss1, dim3(256), dim3(256), 0, stream, lpart, lp2);
    hipLaunchKernelGGL(vq_loss2, dim3(1), dim3(256), 0, stream, lp2, loss);
}